// Round 8
// baseline (756.237 us; speedup 1.0000x reference)
//
#include <hip/hip_runtime.h>

#define N_NODES 20000
#define N_EDGES 640000
#define FDIM 64
#define NB 20
#define LN_EPS 1e-5f

typedef __attribute__((ext_vector_type(8))) short bf16x8;
typedef __attribute__((ext_vector_type(4))) float f32x4;

#define SEL_HI 0x07060302u
#define SEL_LO 0x05040100u
#define MFMA16 __builtin_amdgcn_mfma_f32_16x16x32_bf16

__device__ __forceinline__ float silu_f(float x) { return x / (1.0f + __expf(-x)); }

__device__ __forceinline__ float bcast_lane(float v, int lane) {
    return __int_as_float(__builtin_amdgcn_readlane(__float_as_int(v), lane));
}

__device__ __forceinline__ unsigned bf16_rn(float x) {
    unsigned u = __float_as_uint(x);
    return (u + 0x7FFFu + ((u >> 16) & 1u)) >> 16;
}

__device__ __forceinline__ unsigned pack_split(float x) {
    unsigned h = bf16_rn(x);
    unsigned lo = bf16_rn(x - __uint_as_float(h << 16));
    return (h << 16) | lo;
}

__device__ __forceinline__ void load_afrag(const unsigned* rowPtr, int kh, int q,
                                           bf16x8* ahi, bf16x8* alo) {
    const uint4 ra = *(const uint4*)(rowPtr + kh * 32 + q * 8);
    const uint4 rb = *(const uint4*)(rowPtr + kh * 32 + q * 8 + 4);
    union { unsigned u[4]; bf16x8 v; } H, L;
    H.u[0] = __builtin_amdgcn_perm(ra.y, ra.x, SEL_HI);
    H.u[1] = __builtin_amdgcn_perm(ra.w, ra.z, SEL_HI);
    H.u[2] = __builtin_amdgcn_perm(rb.y, rb.x, SEL_HI);
    H.u[3] = __builtin_amdgcn_perm(rb.w, rb.z, SEL_HI);
    L.u[0] = __builtin_amdgcn_perm(ra.y, ra.x, SEL_LO);
    L.u[1] = __builtin_amdgcn_perm(ra.w, ra.z, SEL_LO);
    L.u[2] = __builtin_amdgcn_perm(rb.y, rb.x, SEL_LO);
    L.u[3] = __builtin_amdgcn_perm(rb.w, rb.z, SEL_LO);
    *ahi = H.v;
    *alo = L.v;
}

__device__ __forceinline__ void mm3(const unsigned* Bhi, const unsigned* Blo,
                                    bf16x8 ahi, bf16x8 alo, f32x4* acc, int kh, int l) {
#pragma unroll
    for (int c = 0; c < 4; ++c) {
        bf16x8 bh = *(const bf16x8*)(Bhi + (kh * 4 + c) * 256 + l * 4);
        bf16x8 bl = *(const bf16x8*)(Blo + (kh * 4 + c) * 256 + l * 4);
        acc[c] = MFMA16(ahi, bh, acc[c], 0, 0, 0);
        acc[c] = MFMA16(ahi, bl, acc[c], 0, 0, 0);
        acc[c] = MFMA16(alo, bh, acc[c], 0, 0, 0);
    }
}

// ---------------- Kernel A: node MLP ----------------
__global__ __launch_bounds__(256) void node_mlp_kernel(
    const float* __restrict__ atom, const float* __restrict__ W1, const float* __restrict__ b1,
    const float* __restrict__ W2, const float* __restrict__ b2, float* __restrict__ mn)
{
    __shared__ float W1s[FDIM][FDIM];
    __shared__ float W2s[FDIM][FDIM];
    const int f = threadIdx.x, ty = threadIdx.y;
    const int tid = ty * 64 + f;
    for (int i = tid; i < FDIM * FDIM; i += 256) {
        ((float*)W1s)[i] = W1[i];
        ((float*)W2s)[i] = W2[i];
    }
    __syncthreads();
    const float bb1 = b1[f], bb2 = b2[f];
    const int nw = gridDim.x * 4;
    for (int n = blockIdx.x * 4 + ty; n < N_NODES; n += nw) {
        const float a = atom[n * FDIM + f];
        float h = bb1;
        for (int g = 0; g < FDIM; ++g) h += bcast_lane(a, g) * W1s[g][f];
        h = silu_f(h);
        float o = bb2;
        for (int g = 0; g < FDIM; ++g) o += bcast_lane(h, g) * W2s[g][f];
        mn[n * FDIM + f] = o;
    }
}

// ---------------- CSR build: hist -> scan -> permute ----------------
__global__ __launch_bounds__(256) void hist_kernel(const int* __restrict__ eidx, int* __restrict__ cursor) {
    for (int e = blockIdx.x * 256 + threadIdx.x; e < N_EDGES; e += gridDim.x * 256)
        atomicAdd(&cursor[eidx[e]], 1);
}

__global__ __launch_bounds__(1024) void scan_kernel(int* __restrict__ cursor) {
    __shared__ int part[1024];
    const int t = threadIdx.x;
    int loc[20];
    int s = 0;
#pragma unroll
    for (int i = 0; i < 20; ++i) {
        const int idx = t * 20 + i;
        const int v = (idx < N_NODES) ? cursor[idx] : 0;
        loc[i] = s;
        s += v;
    }
    part[t] = s;
    __syncthreads();
    for (int off = 1; off < 1024; off <<= 1) {
        int v = (t >= off) ? part[t - off] : 0;
        __syncthreads();
        part[t] += v;
        __syncthreads();
    }
    const int excl = (t == 0) ? 0 : part[t - 1];
#pragma unroll
    for (int i = 0; i < 20; ++i) {
        const int idx = t * 20 + i;
        if (idx < N_NODES) cursor[idx] = excl + loc[i];
    }
}

__global__ __launch_bounds__(256) void permute_kernel(
    const int* __restrict__ eidx, const float* __restrict__ dir,
    int* __restrict__ cursor, int* __restrict__ perm, uint4* __restrict__ meta)
{
    for (int e = blockIdx.x * 256 + threadIdx.x; e < N_EDGES; e += gridDim.x * 256) {
        const int src = eidx[e];
        const int dst = eidx[N_EDGES + e];
        const int pos = atomicAdd(&cursor[src], 1);
        perm[pos] = e;
        uint4 m0, m1;
        m0.x = (unsigned)src;
        m0.y = (unsigned)dst;
        m0.z = __float_as_uint(dir[e * 3 + 0]);
        m0.w = __float_as_uint(dir[e * 3 + 1]);
        m1.x = __float_as_uint(dir[e * 3 + 2]);
        m1.y = 0; m1.z = 0; m1.w = 0;
        meta[(size_t)pos * 2] = m0;
        meta[(size_t)pos * 2 + 1] = m1;
    }
}

// ---------------- Kernel B (CSR): per-edge MFMA pipeline over src-sorted edges ----------------
__global__ __launch_bounds__(1024) void edge_kernel_csr(
    const float* __restrict__ dist,   // [E,20] (indirect via perm)
    const int* __restrict__ perm,     // [E] sorted position -> original edge
    const uint2* __restrict__ meta,   // [E*4] {src,dst}{d0,d1}{d2,0}{0,0}
    const float* __restrict__ mn,     // [N,F]
    const float* __restrict__ We,     // [20,F]
    const float* __restrict__ Wq1a, const float* __restrict__ Wq1b,
    const float* __restrict__ Wq2a, const float* __restrict__ Wq2b,
    const float* __restrict__ forceN, // [N,3,F]
    float* __restrict__ atomAcc,      // [N,F]
    float* __restrict__ forceAcc)     // [N,3,F]
{
    __shared__ __align__(16) unsigned Bfr[16384];
    __shared__ __align__(16) unsigned WeFr[2048];
    __shared__ __align__(16) unsigned Astg[16][16][76];

    const int l = threadIdx.x;
    const int ty = threadIdx.y;
    const int q = l >> 4, row = l & 15;

    for (int t = ty; t < 32; t += 16) {
        const int mm = t >> 3, kh = (t >> 2) & 1, c = t & 3;
        const float* W = (mm == 0) ? Wq1a : (mm == 1) ? Wq2a : (mm == 2) ? Wq1b : Wq2b;
        const int n = c * 16 + row;
        const int kb = kh * 32 + q * 8;
        unsigned* hiP = &Bfr[(((mm * 2 + 0) * 2 + kh) * 4 + c) * 256 + l * 4];
        unsigned* loP = &Bfr[(((mm * 2 + 1) * 2 + kh) * 4 + c) * 256 + l * 4];
#pragma unroll
        for (int i = 0; i < 4; ++i) {
            float w0 = W[(kb + 2 * i) * FDIM + n];
            float w1 = W[(kb + 2 * i + 1) * FDIM + n];
            unsigned h0 = bf16_rn(w0);
            unsigned l0 = bf16_rn(w0 - __uint_as_float(h0 << 16));
            unsigned h1 = bf16_rn(w1);
            unsigned l1 = bf16_rn(w1 - __uint_as_float(h1 << 16));
            hiP[i] = h0 | (h1 << 16);
            loP[i] = l0 | (l1 << 16);
        }
    }
    for (int c = ty; c < 4; c += 16) {
        const int n = c * 16 + row;
        unsigned* hiP = &WeFr[(0 * 4 + c) * 256 + l * 4];
        unsigned* loP = &WeFr[(1 * 4 + c) * 256 + l * 4];
#pragma unroll
        for (int i = 0; i < 4; ++i) {
            const int k0 = q * 8 + 2 * i, k1 = k0 + 1;
            float w0 = (k0 < NB) ? We[k0 * FDIM + n] : 0.0f;
            float w1 = (k1 < NB) ? We[k1 * FDIM + n] : 0.0f;
            unsigned h0 = bf16_rn(w0);
            unsigned l0 = bf16_rn(w0 - __uint_as_float(h0 << 16));
            unsigned h1 = bf16_rn(w1);
            unsigned l1 = bf16_rn(w1 - __uint_as_float(h1 << 16));
            hiP[i] = h0 | (h1 << 16);
            loP[i] = l0 | (l1 << 16);
        }
    }
    __syncthreads();

    const unsigned* B1aH = Bfr + 0 * 2048; const unsigned* B1aL = Bfr + 1 * 2048;
    const unsigned* B2aH = Bfr + 2 * 2048; const unsigned* B2aL = Bfr + 3 * 2048;
    const unsigned* B1bH = Bfr + 4 * 2048; const unsigned* B1bL = Bfr + 5 * 2048;
    const unsigned* B2bH = Bfr + 6 * 2048; const unsigned* B2bL = Bfr + 7 * 2048;
    const unsigned* WeH = WeFr;            const unsigned* WeL = WeFr + 1024;

    unsigned* stg = &Astg[ty][0][0];
    const unsigned* rowPtr = &Astg[ty][row][0];

    const int ngroups = N_EDGES / 16;
    const int stride = gridDim.x * 16;
    for (int grp = blockIdx.x * 16 + ty; grp < ngroups; grp += stride) {
        const int e0 = grp * 16;

        // edge metadata (sorted positions): lane l holds uint2 word-pair l%4 of edge l/4
        const uint2 md = meta[(size_t)e0 * 4 + l];
        const float fx = __uint_as_float(md.x);
        const float fy = __uint_as_float(md.y);

        // ---- me = dist16x20 @ We20x64 via MFMA (dist rows via perm indirection) ----
        const int pe = perm[e0 + row];
        const float* dp = dist + (size_t)pe * NB + q * 8;
        float4 da = {0.f, 0.f, 0.f, 0.f}, db = {0.f, 0.f, 0.f, 0.f};
        if (q < 2)       { da = *(const float4*)dp; db = *(const float4*)(dp + 4); }
        else if (q == 2) { da = *(const float4*)dp; }
        unsigned s0 = pack_split(da.x), s1 = pack_split(da.y);
        unsigned s2 = pack_split(da.z), s3 = pack_split(da.w);
        unsigned s4 = pack_split(db.x), s5 = pack_split(db.y);
        unsigned s6 = pack_split(db.z), s7 = pack_split(db.w);
        union { unsigned u[4]; bf16x8 v; } AH, AL;
        AH.u[0] = __builtin_amdgcn_perm(s1, s0, SEL_HI);
        AH.u[1] = __builtin_amdgcn_perm(s3, s2, SEL_HI);
        AH.u[2] = __builtin_amdgcn_perm(s5, s4, SEL_HI);
        AH.u[3] = __builtin_amdgcn_perm(s7, s6, SEL_HI);
        AL.u[0] = __builtin_amdgcn_perm(s1, s0, SEL_LO);
        AL.u[1] = __builtin_amdgcn_perm(s3, s2, SEL_LO);
        AL.u[2] = __builtin_amdgcn_perm(s5, s4, SEL_LO);
        AL.u[3] = __builtin_amdgcn_perm(s7, s6, SEL_LO);

        f32x4 me4[4];
#pragma unroll
        for (int c = 0; c < 4; ++c) me4[c] = (f32x4){0.f, 0.f, 0.f, 0.f};
        mm3(WeH, WeL, AH.v, AL.v, me4, 0, l);

#pragma unroll
        for (int c = 0; c < 4; ++c)
#pragma unroll
            for (int r = 0; r < 4; ++r)
                stg[(q * 4 + r) * 76 + (row + 16 * c)] = __float_as_uint(me4[c][r]);

        // ---- per-edge msg + run-length-aggregated atomAcc scatter (src sorted) ----
        const int src0 = __builtin_amdgcn_readlane(md.x, 0);
        int cur = src0;
        float msum = 0.0f;
        float mns = mn[(size_t)cur * FDIM + l];
#pragma unroll
        for (int j = 0; j < 16; ++j) {
            const int sj = __builtin_amdgcn_readlane(md.x, 4 * j);
            const int dj = __builtin_amdgcn_readlane(md.y, 4 * j);
            if (sj != cur) {
                atomicAdd(&atomAcc[(size_t)cur * FDIM + l], msum);
                msum = 0.0f;
                cur = sj;
                mns = mn[(size_t)sj * FDIM + l];
            }
            const float me = __uint_as_float(stg[j * 76 + l]);
            const float m = me * mns * mn[(size_t)dj * FDIM + l];
            msum += m;
            stg[j * 76 + l] = pack_split(m);
        }
        atomicAdd(&atomAcc[(size_t)cur * FDIM + l], msum);

        // ---- h-phase ----
        f32x4 acc1[4], acc2[4];
#pragma unroll
        for (int c = 0; c < 4; ++c) {
            acc1[c] = (f32x4){0.f, 0.f, 0.f, 0.f};
            acc2[c] = (f32x4){0.f, 0.f, 0.f, 0.f};
        }
#pragma unroll
        for (int kh = 0; kh < 2; ++kh) {
            bf16x8 ahi, alo;
            load_afrag(rowPtr, kh, q, &ahi, &alo);
            mm3(B1aH, B1aL, ahi, alo, acc1, kh, l);
            mm3(B2aH, B2aL, ahi, alo, acc2, kh, l);
        }
#pragma unroll
        for (int c = 0; c < 4; ++c)
#pragma unroll
            for (int r = 0; r < 4; ++r) {
                acc1[c][r] = silu_f(acc1[c][r]);
                acc2[c][r] = silu_f(acc2[c][r]);
            }

#pragma unroll
        for (int c = 0; c < 4; ++c)
#pragma unroll
            for (int r = 0; r < 4; ++r)
                stg[(q * 4 + r) * 76 + (row + 16 * c)] = pack_split(acc1[c][r]);

        f32x4 eacc1[4];
#pragma unroll
        for (int c = 0; c < 4; ++c) eacc1[c] = (f32x4){0.f, 0.f, 0.f, 0.f};
#pragma unroll
        for (int kh = 0; kh < 2; ++kh) {
            bf16x8 ahi, alo;
            load_afrag(rowPtr, kh, q, &ahi, &alo);
            mm3(B1bH, B1bL, ahi, alo, eacc1, kh, l);
        }

#pragma unroll
        for (int c = 0; c < 4; ++c)
#pragma unroll
            for (int r = 0; r < 4; ++r)
                stg[(q * 4 + r) * 76 + (row + 16 * c)] = pack_split(acc2[c][r]);

        f32x4 eacc2[4];
#pragma unroll
        for (int c = 0; c < 4; ++c) eacc2[c] = (f32x4){0.f, 0.f, 0.f, 0.f};
#pragma unroll
        for (int kh = 0; kh < 2; ++kh) {
            bf16x8 ahi, alo;
            load_afrag(rowPtr, kh, q, &ahi, &alo);
            mm3(B2bH, B2bL, ahi, alo, eacc2, kh, l);
        }

        // ---- equivariant scatter ----
        const int src15 = __builtin_amdgcn_readlane(md.x, 60);
        if (src0 == src15) {
            // uniform-src group: reduce over edges in-register, 4 atomics total
            float t0[4] = {0.f, 0.f, 0.f, 0.f};
            float t1[4] = {0.f, 0.f, 0.f, 0.f};
            float t2[4] = {0.f, 0.f, 0.f, 0.f};
#pragma unroll
            for (int r = 0; r < 4; ++r) {
                const int eo = q * 4 + r;
                const int vd = __shfl((int)md.y, eo * 4);
                const float d0 = __shfl(fx, eo * 4 + 1);
                const float d1 = __shfl(fy, eo * 4 + 1);
                const float d2 = __shfl(fx, eo * 4 + 2);
                const float* fd = forceN + (size_t)vd * 3 * FDIM;
#pragma unroll
                for (int c = 0; c < 4; ++c) {
                    const int n = row + 16 * c;
                    const float a = eacc1[c][r];
                    const float b = eacc2[c][r];
                    t0[c] += a * d0 + b * fd[0 * FDIM + n];
                    t1[c] += a * d1 + b * fd[1 * FDIM + n];
                    t2[c] += a * d2 + b * fd[2 * FDIM + n];
                }
            }
#pragma unroll
            for (int c = 0; c < 4; ++c) {
                t0[c] += __shfl_xor(t0[c], 16, 64); t0[c] += __shfl_xor(t0[c], 32, 64);
                t1[c] += __shfl_xor(t1[c], 16, 64); t1[c] += __shfl_xor(t1[c], 32, 64);
                t2[c] += __shfl_xor(t2[c], 16, 64); t2[c] += __shfl_xor(t2[c], 32, 64);
            }
            float* fa = forceAcc + (size_t)src0 * 3 * FDIM;
#pragma unroll
            for (int c = 0; c < 4; ++c) {
                const float v = (q == 0) ? t0[c] : (q == 1) ? t1[c] : t2[c];
                if (q < 3) atomicAdd(&fa[q * FDIM + row + 16 * c], v);
            }
        } else {
            // mixed-src group: per-edge atomics
#pragma unroll
            for (int r = 0; r < 4; ++r) {
                const int eo = q * 4 + r;
                const int vs = __shfl((int)md.x, eo * 4);
                const int vd = __shfl((int)md.y, eo * 4);
                const float d0 = __shfl(fx, eo * 4 + 1);
                const float d1 = __shfl(fy, eo * 4 + 1);
                const float d2 = __shfl(fx, eo * 4 + 2);
                const float* fd = forceN + (size_t)vd * 3 * FDIM;
                float* fa = forceAcc + (size_t)vs * 3 * FDIM;
#pragma unroll
                for (int c = 0; c < 4; ++c) {
                    const int n = row + 16 * c;
                    const float a = eacc1[c][r];
                    const float b = eacc2[c][r];
                    atomicAdd(&fa[0 * FDIM + n], a * d0 + b * fd[0 * FDIM + n]);
                    atomicAdd(&fa[1 * FDIM + n], a * d1 + b * fd[1 * FDIM + n]);
                    atomicAdd(&fa[2 * FDIM + n], a * d2 + b * fd[2 * FDIM + n]);
                }
            }
        }
    }
}

// ---------------- Fallback edge kernel (R7, unsorted) ----------------
__global__ __launch_bounds__(1024) void edge_kernel_old(
    const float* __restrict__ dist, const float* __restrict__ dir,
    const int* __restrict__ eidx, const float* __restrict__ mn,
    const float* __restrict__ We,
    const float* __restrict__ Wq1a, const float* __restrict__ Wq1b,
    const float* __restrict__ Wq2a, const float* __restrict__ Wq2b,
    const float* __restrict__ forceN,
    float* __restrict__ atomAcc, float* __restrict__ forceAcc)
{
    __shared__ __align__(16) unsigned Bfr[16384];
    __shared__ __align__(16) unsigned WeFr[2048];
    __shared__ __align__(16) unsigned Astg[16][16][76];

    const int l = threadIdx.x;
    const int ty = threadIdx.y;
    const int q = l >> 4, row = l & 15;

    for (int t = ty; t < 32; t += 16) {
        const int mm = t >> 3, kh = (t >> 2) & 1, c = t & 3;
        const float* W = (mm == 0) ? Wq1a : (mm == 1) ? Wq2a : (mm == 2) ? Wq1b : Wq2b;
        const int n = c * 16 + row;
        const int kb = kh * 32 + q * 8;
        unsigned* hiP = &Bfr[(((mm * 2 + 0) * 2 + kh) * 4 + c) * 256 + l * 4];
        unsigned* loP = &Bfr[(((mm * 2 + 1) * 2 + kh) * 4 + c) * 256 + l * 4];
#pragma unroll
        for (int i = 0; i < 4; ++i) {
            float w0 = W[(kb + 2 * i) * FDIM + n];
            float w1 = W[(kb + 2 * i + 1) * FDIM + n];
            unsigned h0 = bf16_rn(w0);
            unsigned l0 = bf16_rn(w0 - __uint_as_float(h0 << 16));
            unsigned h1 = bf16_rn(w1);
            unsigned l1 = bf16_rn(w1 - __uint_as_float(h1 << 16));
            hiP[i] = h0 | (h1 << 16);
            loP[i] = l0 | (l1 << 16);
        }
    }
    for (int c = ty; c < 4; c += 16) {
        const int n = c * 16 + row;
        unsigned* hiP = &WeFr[(0 * 4 + c) * 256 + l * 4];
        unsigned* loP = &WeFr[(1 * 4 + c) * 256 + l * 4];
#pragma unroll
        for (int i = 0; i < 4; ++i) {
            const int k0 = q * 8 + 2 * i, k1 = k0 + 1;
            float w0 = (k0 < NB) ? We[k0 * FDIM + n] : 0.0f;
            float w1 = (k1 < NB) ? We[k1 * FDIM + n] : 0.0f;
            unsigned h0 = bf16_rn(w0);
            unsigned l0 = bf16_rn(w0 - __uint_as_float(h0 << 16));
            unsigned h1 = bf16_rn(w1);
            unsigned l1 = bf16_rn(w1 - __uint_as_float(h1 << 16));
            hiP[i] = h0 | (h1 << 16);
            loP[i] = l0 | (l1 << 16);
        }
    }
    __syncthreads();

    const unsigned* B1aH = Bfr + 0 * 2048; const unsigned* B1aL = Bfr + 1 * 2048;
    const unsigned* B2aH = Bfr + 2 * 2048; const unsigned* B2aL = Bfr + 3 * 2048;
    const unsigned* B1bH = Bfr + 4 * 2048; const unsigned* B1bL = Bfr + 5 * 2048;
    const unsigned* B2bH = Bfr + 6 * 2048; const unsigned* B2bL = Bfr + 7 * 2048;
    const unsigned* WeH = WeFr;            const unsigned* WeL = WeFr + 1024;

    unsigned* stg = &Astg[ty][0][0];
    const unsigned* rowPtr = &Astg[ty][row][0];

    const int ngroups = N_EDGES / 16;
    const int stride = gridDim.x * 16;
    for (int grp = blockIdx.x * 16 + ty; grp < ngroups; grp += stride) {
        const int e0 = grp * 16;
        int ev = 0;
        if (l < 32) ev = eidx[(l < 16) ? (e0 + l) : (N_EDGES + e0 + (l - 16))];
        float dv = (l < 48) ? dir[e0 * 3 + l] : 0.0f;

        const float* dp = dist + (size_t)(e0 + row) * NB + q * 8;
        float4 da = {0.f, 0.f, 0.f, 0.f}, db = {0.f, 0.f, 0.f, 0.f};
        if (q < 2)       { da = *(const float4*)dp; db = *(const float4*)(dp + 4); }
        else if (q == 2) { da = *(const float4*)dp; }
        unsigned s0 = pack_split(da.x), s1 = pack_split(da.y);
        unsigned s2 = pack_split(da.z), s3 = pack_split(da.w);
        unsigned s4 = pack_split(db.x), s5 = pack_split(db.y);
        unsigned s6 = pack_split(db.z), s7 = pack_split(db.w);
        union { unsigned u[4]; bf16x8 v; } AH, AL;
        AH.u[0] = __builtin_amdgcn_perm(s1, s0, SEL_HI);
        AH.u[1] = __builtin_amdgcn_perm(s3, s2, SEL_HI);
        AH.u[2] = __builtin_amdgcn_perm(s5, s4, SEL_HI);
        AH.u[3] = __builtin_amdgcn_perm(s7, s6, SEL_HI);
        AL.u[0] = __builtin_amdgcn_perm(s1, s0, SEL_LO);
        AL.u[1] = __builtin_amdgcn_perm(s3, s2, SEL_LO);
        AL.u[2] = __builtin_amdgcn_perm(s5, s4, SEL_LO);
        AL.u[3] = __builtin_amdgcn_perm(s7, s6, SEL_LO);

        f32x4 me4[4];
#pragma unroll
        for (int c = 0; c < 4; ++c) me4[c] = (f32x4){0.f, 0.f, 0.f, 0.f};
        mm3(WeH, WeL, AH.v, AL.v, me4, 0, l);
#pragma unroll
        for (int c = 0; c < 4; ++c)
#pragma unroll
            for (int r = 0; r < 4; ++r)
                stg[(q * 4 + r) * 76 + (row + 16 * c)] = __float_as_uint(me4[c][r]);

#pragma unroll
        for (int j = 0; j < 16; ++j) {
            const int src = __builtin_amdgcn_readlane(ev, j);
            const int dst = __builtin_amdgcn_readlane(ev, 16 + j);
            const float me = __uint_as_float(stg[j * 76 + l]);
            const float m = me * mn[src * FDIM + l] * mn[dst * FDIM + l];
            atomicAdd(&atomAcc[src * FDIM + l], m);
            stg[j * 76 + l] = pack_split(m);
        }

        f32x4 acc1[4], acc2[4];
#pragma unroll
        for (int c = 0; c < 4; ++c) {
            acc1[c] = (f32x4){0.f, 0.f, 0.f, 0.f};
            acc2[c] = (f32x4){0.f, 0.f, 0.f, 0.f};
        }
#pragma unroll
        for (int kh = 0; kh < 2; ++kh) {
            bf16x8 ahi, alo;
            load_afrag(rowPtr, kh, q, &ahi, &alo);
            mm3(B1aH, B1aL, ahi, alo, acc1, kh, l);
            mm3(B2aH, B2aL, ahi, alo, acc2, kh, l);
        }
#pragma unroll
        for (int c = 0; c < 4; ++c)
#pragma unroll
            for (int r = 0; r < 4; ++r) {
                acc1[c][r] = silu_f(acc1[c][r]);
                acc2[c][r] = silu_f(acc2[c][r]);
            }
#pragma unroll
        for (int c = 0; c < 4; ++c)
#pragma unroll
            for (int r = 0; r < 4; ++r)
                stg[(q * 4 + r) * 76 + (row + 16 * c)] = pack_split(acc1[c][r]);
        f32x4 eacc1[4];
#pragma unroll
        for (int c = 0; c < 4; ++c) eacc1[c] = (f32x4){0.f, 0.f, 0.f, 0.f};
#pragma unroll
        for (int kh = 0; kh < 2; ++kh) {
            bf16x8 ahi, alo;
            load_afrag(rowPtr, kh, q, &ahi, &alo);
            mm3(B1bH, B1bL, ahi, alo, eacc1, kh, l);
        }
#pragma unroll
        for (int c = 0; c < 4; ++c)
#pragma unroll
            for (int r = 0; r < 4; ++r)
                stg[(q * 4 + r) * 76 + (row + 16 * c)] = pack_split(acc2[c][r]);
        f32x4 eacc2[4];
#pragma unroll
        for (int c = 0; c < 4; ++c) eacc2[c] = (f32x4){0.f, 0.f, 0.f, 0.f};
#pragma unroll
        for (int kh = 0; kh < 2; ++kh) {
            bf16x8 ahi, alo;
            load_afrag(rowPtr, kh, q, &ahi, &alo);
            mm3(B2bH, B2bL, ahi, alo, eacc2, kh, l);
        }
#pragma unroll
        for (int r = 0; r < 4; ++r) {
            const int eo = q * 4 + r;
            const int vs = __shfl(ev, eo);
            const int vd = __shfl(ev, 16 + eo);
            const float d0 = __shfl(dv, eo * 3 + 0);
            const float d1 = __shfl(dv, eo * 3 + 1);
            const float d2 = __shfl(dv, eo * 3 + 2);
            const float* fd = forceN + (size_t)vd * 3 * FDIM;
            float* fa = forceAcc + (size_t)vs * 3 * FDIM;
#pragma unroll
            for (int c = 0; c < 4; ++c) {
                const int n = row + 16 * c;
                const float a = eacc1[c][r];
                const float b = eacc2[c][r];
                atomicAdd(&fa[0 * FDIM + n], a * d0 + b * fd[0 * FDIM + n]);
                atomicAdd(&fa[1 * FDIM + n], a * d1 + b * fd[1 * FDIM + n]);
                atomicAdd(&fa[2 * FDIM + n], a * d2 + b * fd[2 * FDIM + n]);
            }
        }
    }
}

// ---------------- Kernel C: finalize nodes ----------------
__global__ __launch_bounds__(256) void node_final_kernel(
    const float* __restrict__ Wu, const float* __restrict__ gamma, const float* __restrict__ beta,
    float* __restrict__ atomAcc, const float* __restrict__ forceOut)
{
    __shared__ float Wus[FDIM][FDIM];
    const int f = threadIdx.x, ty = threadIdx.y;
    const int tid = ty * 64 + f;
    for (int i = tid; i < FDIM * FDIM; i += 256) ((float*)Wus)[i] = Wu[i];
    __syncthreads();
    const float gg = gamma[f], bb = beta[f];
    const int nw = gridDim.x * 4;
    for (int n = blockIdx.x * 4 + ty; n < N_NODES; n += nw) {
        const float f0 = forceOut[((size_t)n * 3 + 0) * FDIM + f];
        const float f1 = forceOut[((size_t)n * 3 + 1) * FDIM + f];
        const float f2 = forceOut[((size_t)n * 3 + 2) * FDIM + f];
        float r0 = 0.0f, r1 = 0.0f, r2 = 0.0f;
#pragma unroll 8
        for (int g = 0; g < FDIM; ++g) {
            const float w = Wus[g][f];
            r0 += bcast_lane(f0, g) * w;
            r1 += bcast_lane(f1, g) * w;
            r2 += bcast_lane(f2, g) * w;
        }
        float a = atomAcc[n * FDIM + f] + (f0 * r0 + f1 * r1 + f2 * r2);
        float s = a;
#pragma unroll
        for (int off = 32; off >= 1; off >>= 1) s += __shfl_xor(s, off, 64);
        const float mu = s * (1.0f / 64.0f);
        const float d = a - mu;
        float v = d * d;
#pragma unroll
        for (int off = 32; off >= 1; off >>= 1) v += __shfl_xor(v, off, 64);
        v *= (1.0f / 64.0f);
        atomAcc[n * FDIM + f] = d * rsqrtf(v + LN_EPS) * gg + bb;
    }
}

extern "C" void kernel_launch(void* const* d_in, const int* in_sizes, int n_in,
                              void* d_out, int out_size, void* d_ws, size_t ws_size,
                              hipStream_t stream)
{
    const float* atom_node  = (const float*)d_in[0];
    const float* force_node = (const float*)d_in[1];
    const float* dir_edge   = (const float*)d_in[2];
    const float* dist_edge  = (const float*)d_in[3];
    const int*   edge_index = (const int*)d_in[4];
    const float* W1   = (const float*)d_in[5];
    const float* b1   = (const float*)d_in[6];
    const float* W2   = (const float*)d_in[7];
    const float* b2   = (const float*)d_in[8];
    const float* We   = (const float*)d_in[9];
    const float* Wq1a = (const float*)d_in[10];
    const float* Wq1b = (const float*)d_in[11];
    const float* Wq2a = (const float*)d_in[12];
    const float* Wq2b = (const float*)d_in[13];
    const float* Wu   = (const float*)d_in[14];
    const float* gamma = (const float*)d_in[15];
    const float* beta  = (const float*)d_in[16];

    float* atomOut  = (float*)d_out;
    float* forceOut = (float*)d_out + (size_t)N_NODES * FDIM;

    // ws layout: mn [5.12MB] | cursor [80KB] | perm [2.56MB] | meta [20.48MB]
    char* ws = (char*)d_ws;
    float* mn    = (float*)ws;
    int* cursor  = (int*)(ws + 5120000);
    int* perm    = (int*)(ws + 5200000);
    uint4* meta  = (uint4*)(ws + 7760000);
    const size_t NEED = 7760000 + (size_t)N_EDGES * 32;

    hipMemcpyAsync(atomOut, atom_node, (size_t)N_NODES * FDIM * sizeof(float),
                   hipMemcpyDeviceToDevice, stream);
    hipMemcpyAsync(forceOut, force_node, (size_t)N_NODES * 3 * FDIM * sizeof(float),
                   hipMemcpyDeviceToDevice, stream);

    dim3 blk4(64, 4);
    dim3 blk16(64, 16);
    node_mlp_kernel<<<512, blk4, 0, stream>>>(atom_node, W1, b1, W2, b2, mn);

    if (ws_size >= NEED) {
        hipMemsetAsync(cursor, 0, N_NODES * sizeof(int), stream);
        hist_kernel<<<1024, 256, 0, stream>>>(edge_index, cursor);
        scan_kernel<<<1, 1024, 0, stream>>>(cursor);
        permute_kernel<<<1024, 256, 0, stream>>>(edge_index, dir_edge, cursor, perm, meta);
        edge_kernel_csr<<<256, blk16, 0, stream>>>(dist_edge, perm, (const uint2*)meta, mn, We,
                                                   Wq1a, Wq1b, Wq2a, Wq2b, force_node,
                                                   atomOut, forceOut);
    } else {
        edge_kernel_old<<<256, blk16, 0, stream>>>(dist_edge, dir_edge, edge_index, mn, We,
                                                   Wq1a, Wq1b, Wq2a, Wq2b, force_node,
                                                   atomOut, forceOut);
    }
    node_final_kernel<<<512, blk4, 0, stream>>>(Wu, gamma, beta, atomOut, forceOut);
}

// Round 9
// 595.055 us; speedup vs baseline: 1.2709x; 1.2709x over previous
//
#include <hip/hip_runtime.h>

#define N_NODES 20000
#define N_EDGES 640000
#define FDIM 64
#define NB 20
#define LN_EPS 1e-5f

typedef __attribute__((ext_vector_type(8))) short bf16x8;
typedef __attribute__((ext_vector_type(4))) float f32x4;

#define SEL_HI 0x07060302u
#define SEL_LO 0x05040100u
#define MFMA16 __builtin_amdgcn_mfma_f32_16x16x32_bf16

__device__ __forceinline__ float silu_f(float x) { return x / (1.0f + __expf(-x)); }

__device__ __forceinline__ float bcast_lane(float v, int lane) {
    return __int_as_float(__builtin_amdgcn_readlane(__float_as_int(v), lane));
}

__device__ __forceinline__ unsigned bf16_rn(float x) {
    unsigned u = __float_as_uint(x);
    return (u + 0x7FFFu + ((u >> 16) & 1u)) >> 16;
}

__device__ __forceinline__ unsigned pack_split(float x) {
    unsigned h = bf16_rn(x);
    unsigned lo = bf16_rn(x - __uint_as_float(h << 16));
    return (h << 16) | lo;
}

__device__ __forceinline__ void load_afrag(const unsigned* rowPtr, int kh, int q,
                                           bf16x8* ahi, bf16x8* alo) {
    const uint4 ra = *(const uint4*)(rowPtr + kh * 32 + q * 8);
    const uint4 rb = *(const uint4*)(rowPtr + kh * 32 + q * 8 + 4);
    union { unsigned u[4]; bf16x8 v; } H, L;
    H.u[0] = __builtin_amdgcn_perm(ra.y, ra.x, SEL_HI);
    H.u[1] = __builtin_amdgcn_perm(ra.w, ra.z, SEL_HI);
    H.u[2] = __builtin_amdgcn_perm(rb.y, rb.x, SEL_HI);
    H.u[3] = __builtin_amdgcn_perm(rb.w, rb.z, SEL_HI);
    L.u[0] = __builtin_amdgcn_perm(ra.y, ra.x, SEL_LO);
    L.u[1] = __builtin_amdgcn_perm(ra.w, ra.z, SEL_LO);
    L.u[2] = __builtin_amdgcn_perm(rb.y, rb.x, SEL_LO);
    L.u[3] = __builtin_amdgcn_perm(rb.w, rb.z, SEL_LO);
    *ahi = H.v;
    *alo = L.v;
}

__device__ __forceinline__ void mm3(const unsigned* Bhi, const unsigned* Blo,
                                    bf16x8 ahi, bf16x8 alo, f32x4* acc, int kh, int l) {
#pragma unroll
    for (int c = 0; c < 4; ++c) {
        bf16x8 bh = *(const bf16x8*)(Bhi + (kh * 4 + c) * 256 + l * 4);
        bf16x8 bl = *(const bf16x8*)(Blo + (kh * 4 + c) * 256 + l * 4);
        acc[c] = MFMA16(ahi, bh, acc[c], 0, 0, 0);
        acc[c] = MFMA16(ahi, bl, acc[c], 0, 0, 0);
        acc[c] = MFMA16(alo, bh, acc[c], 0, 0, 0);
    }
}

// ---------------- Kernel A: node MLP ----------------
__global__ __launch_bounds__(256) void node_mlp_kernel(
    const float* __restrict__ atom, const float* __restrict__ W1, const float* __restrict__ b1,
    const float* __restrict__ W2, const float* __restrict__ b2, float* __restrict__ mn)
{
    __shared__ float W1s[FDIM][FDIM];
    __shared__ float W2s[FDIM][FDIM];
    const int f = threadIdx.x, ty = threadIdx.y;
    const int tid = ty * 64 + f;
    for (int i = tid; i < FDIM * FDIM; i += 256) {
        ((float*)W1s)[i] = W1[i];
        ((float*)W2s)[i] = W2[i];
    }
    __syncthreads();
    const float bb1 = b1[f], bb2 = b2[f];
    const int nw = gridDim.x * 4;
    for (int n = blockIdx.x * 4 + ty; n < N_NODES; n += nw) {
        const float a = atom[n * FDIM + f];
        float h = bb1;
        for (int g = 0; g < FDIM; ++g) h += bcast_lane(a, g) * W1s[g][f];
        h = silu_f(h);
        float o = bb2;
        for (int g = 0; g < FDIM; ++g) o += bcast_lane(h, g) * W2s[g][f];
        mn[n * FDIM + f] = o;
    }
}

// ---------------- Kernel B: per-edge MFMA pipeline, software-pipelined gathers ----------------
// R7 structure + cross-group register prefetch: next group's eidx/dir/dist issued at top,
// next group's 32 mn row-gathers issued right after the msg loop (in-place rotate) so they
// overlap the h/e MFMA phases instead of stalling the next iteration's head.
__global__ __launch_bounds__(1024) void edge_kernel(
    const float* __restrict__ dist,   // [E,20]
    const float* __restrict__ dir,    // [E,3]
    const int* __restrict__ eidx,     // [2,E] int32
    const float* __restrict__ mn,     // [N,F]
    const float* __restrict__ We,     // [20,F]
    const float* __restrict__ Wq1a, const float* __restrict__ Wq1b,
    const float* __restrict__ Wq2a, const float* __restrict__ Wq2b,
    const float* __restrict__ forceN, // [N,3,F]
    float* __restrict__ atomAcc,      // [N,F]
    float* __restrict__ forceAcc)     // [N,3,F]
{
    __shared__ __align__(16) unsigned Bfr[16384];         // 64 KB weight frags
    __shared__ __align__(16) unsigned WeFr[2048];         // 8 KB We frags
    __shared__ __align__(16) unsigned Astg[16][16][76];   // per-wave staging

    const int l = threadIdx.x;
    const int ty = threadIdx.y;
    const int q = l >> 4, row = l & 15;

    for (int t = ty; t < 32; t += 16) {
        const int mm = t >> 3, kh = (t >> 2) & 1, c = t & 3;
        const float* W = (mm == 0) ? Wq1a : (mm == 1) ? Wq2a : (mm == 2) ? Wq1b : Wq2b;
        const int n = c * 16 + row;
        const int kb = kh * 32 + q * 8;
        unsigned* hiP = &Bfr[(((mm * 2 + 0) * 2 + kh) * 4 + c) * 256 + l * 4];
        unsigned* loP = &Bfr[(((mm * 2 + 1) * 2 + kh) * 4 + c) * 256 + l * 4];
#pragma unroll
        for (int i = 0; i < 4; ++i) {
            float w0 = W[(kb + 2 * i) * FDIM + n];
            float w1 = W[(kb + 2 * i + 1) * FDIM + n];
            unsigned h0 = bf16_rn(w0);
            unsigned l0 = bf16_rn(w0 - __uint_as_float(h0 << 16));
            unsigned h1 = bf16_rn(w1);
            unsigned l1 = bf16_rn(w1 - __uint_as_float(h1 << 16));
            hiP[i] = h0 | (h1 << 16);
            loP[i] = l0 | (l1 << 16);
        }
    }
    for (int c = ty; c < 4; c += 16) {
        const int n = c * 16 + row;
        unsigned* hiP = &WeFr[(0 * 4 + c) * 256 + l * 4];
        unsigned* loP = &WeFr[(1 * 4 + c) * 256 + l * 4];
#pragma unroll
        for (int i = 0; i < 4; ++i) {
            const int k0 = q * 8 + 2 * i, k1 = k0 + 1;
            float w0 = (k0 < NB) ? We[k0 * FDIM + n] : 0.0f;
            float w1 = (k1 < NB) ? We[k1 * FDIM + n] : 0.0f;
            unsigned h0 = bf16_rn(w0);
            unsigned l0 = bf16_rn(w0 - __uint_as_float(h0 << 16));
            unsigned h1 = bf16_rn(w1);
            unsigned l1 = bf16_rn(w1 - __uint_as_float(h1 << 16));
            hiP[i] = h0 | (h1 << 16);
            loP[i] = l0 | (l1 << 16);
        }
    }
    __syncthreads();

    const unsigned* B1aH = Bfr + 0 * 2048; const unsigned* B1aL = Bfr + 1 * 2048;
    const unsigned* B2aH = Bfr + 2 * 2048; const unsigned* B2aL = Bfr + 3 * 2048;
    const unsigned* B1bH = Bfr + 4 * 2048; const unsigned* B1bL = Bfr + 5 * 2048;
    const unsigned* B2bH = Bfr + 6 * 2048; const unsigned* B2bL = Bfr + 7 * 2048;
    const unsigned* WeH = WeFr;            const unsigned* WeL = WeFr + 1024;

    unsigned* stg = &Astg[ty][0][0];
    const unsigned* rowPtr = &Astg[ty][row][0];

    const int ngroups = N_EDGES / 16;
    const int stride = gridDim.x * 16;
    int grp = blockIdx.x * 16 + ty;

    // ---- prologue: load group 'grp' metadata + mn gathers ----
    int e0 = grp * 16;
    int evA = (l < 32) ? eidx[(l < 16) ? (e0 + l) : (N_EDGES + e0 + (l - 16))] : 0;
    float dvA = (l < 48) ? dir[e0 * 3 + l] : 0.0f;
    float4 daA = {0.f, 0.f, 0.f, 0.f}, dbA = {0.f, 0.f, 0.f, 0.f};
    {
        const float* dp = dist + (size_t)(e0 + row) * NB + q * 8;
        if (q < 2)       { daA = *(const float4*)dp; dbA = *(const float4*)(dp + 4); }
        else if (q == 2) { daA = *(const float4*)dp; }
    }
    float mnS[16], mnD[16];
#pragma unroll
    for (int j = 0; j < 16; ++j) {
        const int src = __builtin_amdgcn_readlane(evA, j);
        const int dst = __builtin_amdgcn_readlane(evA, 16 + j);
        mnS[j] = mn[(size_t)src * FDIM + l];
        mnD[j] = mn[(size_t)dst * FDIM + l];
    }

    while (grp < ngroups) {
        e0 = grp * 16;
        const int grpN = grp + stride;
        const int e0n = (grpN < ngroups) ? grpN * 16 : 0;

        // ---- issue next-group metadata loads (fly under me-phase) ----
        const int evB = (l < 32) ? eidx[(l < 16) ? (e0n + l) : (N_EDGES + e0n + (l - 16))] : 0;
        const float dvB = (l < 48) ? dir[e0n * 3 + l] : 0.0f;

        // ---- me = dist16x20 @ We20x64 via MFMA using prefetched daA/dbA ----
        unsigned s0 = pack_split(daA.x), s1 = pack_split(daA.y);
        unsigned s2 = pack_split(daA.z), s3 = pack_split(daA.w);
        unsigned s4 = pack_split(dbA.x), s5 = pack_split(dbA.y);
        unsigned s6 = pack_split(dbA.z), s7 = pack_split(dbA.w);
        union { unsigned u[4]; bf16x8 v; } AH, AL;
        AH.u[0] = __builtin_amdgcn_perm(s1, s0, SEL_HI);
        AH.u[1] = __builtin_amdgcn_perm(s3, s2, SEL_HI);
        AH.u[2] = __builtin_amdgcn_perm(s5, s4, SEL_HI);
        AH.u[3] = __builtin_amdgcn_perm(s7, s6, SEL_HI);
        AL.u[0] = __builtin_amdgcn_perm(s1, s0, SEL_LO);
        AL.u[1] = __builtin_amdgcn_perm(s3, s2, SEL_LO);
        AL.u[2] = __builtin_amdgcn_perm(s5, s4, SEL_LO);
        AL.u[3] = __builtin_amdgcn_perm(s7, s6, SEL_LO);

        f32x4 me4[4];
#pragma unroll
        for (int c = 0; c < 4; ++c) me4[c] = (f32x4){0.f, 0.f, 0.f, 0.f};
        mm3(WeH, WeL, AH.v, AL.v, me4, 0, l);
#pragma unroll
        for (int c = 0; c < 4; ++c)
#pragma unroll
            for (int r = 0; r < 4; ++r)
                stg[(q * 4 + r) * 76 + (row + 16 * c)] = __float_as_uint(me4[c][r]);

        // ---- issue next-group dist loads (fly under msg + h/e phases) ----
        float4 daB = {0.f, 0.f, 0.f, 0.f}, dbB = {0.f, 0.f, 0.f, 0.f};
        {
            const float* dpn = dist + (size_t)(e0n + row) * NB + q * 8;
            if (q < 2)       { daB = *(const float4*)dpn; dbB = *(const float4*)(dpn + 4); }
            else if (q == 2) { daB = *(const float4*)dpn; }
        }

        // ---- msg loop: uses prefetched mnS/mnD registers (no gather waits) ----
#pragma unroll
        for (int j = 0; j < 16; ++j) {
            const int src = __builtin_amdgcn_readlane(evA, j);
            const float me = __uint_as_float(stg[j * 76 + l]);
            const float m = me * mnS[j] * mnD[j];
            atomicAdd(&atomAcc[(size_t)src * FDIM + l], m);
            stg[j * 76 + l] = pack_split(m);
        }

        // ---- issue next-group mn gathers (in-place rotate; fly under h/e phases) ----
#pragma unroll
        for (int j = 0; j < 16; ++j) {
            const int srcN = __builtin_amdgcn_readlane(evB, j);
            const int dstN = __builtin_amdgcn_readlane(evB, 16 + j);
            mnS[j] = mn[(size_t)srcN * FDIM + l];
            mnD[j] = mn[(size_t)dstN * FDIM + l];
        }

        // ---- h-phase: h1 = msg@Wq1a, h2 = msg@Wq2a ----
        f32x4 acc1[4], acc2[4];
#pragma unroll
        for (int c = 0; c < 4; ++c) {
            acc1[c] = (f32x4){0.f, 0.f, 0.f, 0.f};
            acc2[c] = (f32x4){0.f, 0.f, 0.f, 0.f};
        }
#pragma unroll
        for (int kh = 0; kh < 2; ++kh) {
            bf16x8 ahi, alo;
            load_afrag(rowPtr, kh, q, &ahi, &alo);
            mm3(B1aH, B1aL, ahi, alo, acc1, kh, l);
            mm3(B2aH, B2aL, ahi, alo, acc2, kh, l);
        }
#pragma unroll
        for (int c = 0; c < 4; ++c)
#pragma unroll
            for (int r = 0; r < 4; ++r) {
                acc1[c][r] = silu_f(acc1[c][r]);
                acc2[c][r] = silu_f(acc2[c][r]);
            }

        // ---- stage h1, e1 = h1@Wq1b ----
#pragma unroll
        for (int c = 0; c < 4; ++c)
#pragma unroll
            for (int r = 0; r < 4; ++r)
                stg[(q * 4 + r) * 76 + (row + 16 * c)] = pack_split(acc1[c][r]);
        f32x4 eacc1[4];
#pragma unroll
        for (int c = 0; c < 4; ++c) eacc1[c] = (f32x4){0.f, 0.f, 0.f, 0.f};
#pragma unroll
        for (int kh = 0; kh < 2; ++kh) {
            bf16x8 ahi, alo;
            load_afrag(rowPtr, kh, q, &ahi, &alo);
            mm3(B1bH, B1bL, ahi, alo, eacc1, kh, l);
        }

        // ---- stage h2, e2 = h2@Wq2b ----
#pragma unroll
        for (int c = 0; c < 4; ++c)
#pragma unroll
            for (int r = 0; r < 4; ++r)
                stg[(q * 4 + r) * 76 + (row + 16 * c)] = pack_split(acc2[c][r]);
        f32x4 eacc2[4];
#pragma unroll
        for (int c = 0; c < 4; ++c) eacc2[c] = (f32x4){0.f, 0.f, 0.f, 0.f};
#pragma unroll
        for (int kh = 0; kh < 2; ++kh) {
            bf16x8 ahi, alo;
            load_afrag(rowPtr, kh, q, &ahi, &alo);
            mm3(B2bH, B2bL, ahi, alo, eacc2, kh, l);
        }

        // ---- equivariant scatter ----
#pragma unroll
        for (int r = 0; r < 4; ++r) {
            const int eo = q * 4 + r;
            const int vs = __shfl(evA, eo);
            const int vd = __shfl(evA, 16 + eo);
            const float d0 = __shfl(dvA, eo * 3 + 0);
            const float d1 = __shfl(dvA, eo * 3 + 1);
            const float d2 = __shfl(dvA, eo * 3 + 2);
            const float* fd = forceN + (size_t)vd * 3 * FDIM;
            float* fa = forceAcc + (size_t)vs * 3 * FDIM;
#pragma unroll
            for (int c = 0; c < 4; ++c) {
                const int n = row + 16 * c;
                const float a = eacc1[c][r];
                const float b = eacc2[c][r];
                atomicAdd(&fa[0 * FDIM + n], a * d0 + b * fd[0 * FDIM + n]);
                atomicAdd(&fa[1 * FDIM + n], a * d1 + b * fd[1 * FDIM + n]);
                atomicAdd(&fa[2 * FDIM + n], a * d2 + b * fd[2 * FDIM + n]);
            }
        }

        // ---- rotate prefetched state ----
        evA = evB;
        dvA = dvB;
        daA = daB;
        dbA = dbB;
        grp = grpN;
    }
}

// ---------------- Kernel C: finalize nodes ----------------
__global__ __launch_bounds__(256) void node_final_kernel(
    const float* __restrict__ Wu, const float* __restrict__ gamma, const float* __restrict__ beta,
    float* __restrict__ atomAcc, const float* __restrict__ forceOut)
{
    __shared__ float Wus[FDIM][FDIM];
    const int f = threadIdx.x, ty = threadIdx.y;
    const int tid = ty * 64 + f;
    for (int i = tid; i < FDIM * FDIM; i += 256) ((float*)Wus)[i] = Wu[i];
    __syncthreads();
    const float gg = gamma[f], bb = beta[f];
    const int nw = gridDim.x * 4;
    for (int n = blockIdx.x * 4 + ty; n < N_NODES; n += nw) {
        const float f0 = forceOut[((size_t)n * 3 + 0) * FDIM + f];
        const float f1 = forceOut[((size_t)n * 3 + 1) * FDIM + f];
        const float f2 = forceOut[((size_t)n * 3 + 2) * FDIM + f];
        float r0 = 0.0f, r1 = 0.0f, r2 = 0.0f;
#pragma unroll 8
        for (int g = 0; g < FDIM; ++g) {
            const float w = Wus[g][f];
            r0 += bcast_lane(f0, g) * w;
            r1 += bcast_lane(f1, g) * w;
            r2 += bcast_lane(f2, g) * w;
        }
        float a = atomAcc[n * FDIM + f] + (f0 * r0 + f1 * r1 + f2 * r2);
        float s = a;
#pragma unroll
        for (int off = 32; off >= 1; off >>= 1) s += __shfl_xor(s, off, 64);
        const float mu = s * (1.0f / 64.0f);
        const float d = a - mu;
        float v = d * d;
#pragma unroll
        for (int off = 32; off >= 1; off >>= 1) v += __shfl_xor(v, off, 64);
        v *= (1.0f / 64.0f);
        atomAcc[n * FDIM + f] = d * rsqrtf(v + LN_EPS) * gg + bb;
    }
}

extern "C" void kernel_launch(void* const* d_in, const int* in_sizes, int n_in,
                              void* d_out, int out_size, void* d_ws, size_t ws_size,
                              hipStream_t stream)
{
    const float* atom_node  = (const float*)d_in[0];
    const float* force_node = (const float*)d_in[1];
    const float* dir_edge   = (const float*)d_in[2];
    const float* dist_edge  = (const float*)d_in[3];
    const int*   edge_index = (const int*)d_in[4];
    const float* W1   = (const float*)d_in[5];
    const float* b1   = (const float*)d_in[6];
    const float* W2   = (const float*)d_in[7];
    const float* b2   = (const float*)d_in[8];
    const float* We   = (const float*)d_in[9];
    const float* Wq1a = (const float*)d_in[10];
    const float* Wq1b = (const float*)d_in[11];
    const float* Wq2a = (const float*)d_in[12];
    const float* Wq2b = (const float*)d_in[13];
    const float* Wu   = (const float*)d_in[14];
    const float* gamma = (const float*)d_in[15];
    const float* beta  = (const float*)d_in[16];

    float* atomOut  = (float*)d_out;
    float* forceOut = (float*)d_out + (size_t)N_NODES * FDIM;
    float* mn = (float*)d_ws;

    hipMemcpyAsync(atomOut, atom_node, (size_t)N_NODES * FDIM * sizeof(float),
                   hipMemcpyDeviceToDevice, stream);
    hipMemcpyAsync(forceOut, force_node, (size_t)N_NODES * 3 * FDIM * sizeof(float),
                   hipMemcpyDeviceToDevice, stream);

    dim3 blk4(64, 4);
    dim3 blk16(64, 16);
    node_mlp_kernel<<<512, blk4, 0, stream>>>(atom_node, W1, b1, W2, b2, mn);
    edge_kernel<<<256, blk16, 0, stream>>>(dist_edge, dir_edge, edge_index, mn, We,
                                           Wq1a, Wq1b, Wq2a, Wq2b, force_node,
                                           atomOut, forceOut);
    node_final_kernel<<<512, blk4, 0, stream>>>(Wu, gamma, beta, atomOut, forceOut);
}